// Round 1
// 3728.387 us; speedup vs baseline: 1.4785x; 1.4785x over previous
//
#include <hip/hip_runtime.h>
#include <math.h>

// Problem constants
constexpr int D = 768;
constexpr int H = 12;
constexpr int L = 6;
constexpr int B = 8;
constexpr int S = 256;
constexpr int DH = 64;      // D/H
constexpr int M = B * S;    // 2048 rows
constexpr int D4 = 4 * D;   // 3072

typedef _Float16 v2h __attribute__((ext_vector_type(2)));
typedef _Float16 v4h __attribute__((ext_vector_type(4)));
typedef _Float16 v8h __attribute__((ext_vector_type(8)));
typedef __fp16 f16x2 __attribute__((ext_vector_type(2)));
typedef float v4f __attribute__((ext_vector_type(4)));

// fp32 -> hi/lo fp16 split (Markidis). hi = rtz(x); lo = rtz(x - hi).
__device__ inline void cvt_split(float x, float y, v2h& hi, v2h& lo) {
    f16x2 h = __builtin_amdgcn_cvt_pkrtz(x, y);
    float rx = x - (float)h[0];
    float ry = y - (float)h[1];
    f16x2 l = __builtin_amdgcn_cvt_pkrtz(rx, ry);
    hi = __builtin_bit_cast(v2h, h);
    lo = __builtin_bit_cast(v2h, l);
}

// ---------------------------------------------------------------------------
// Split-fp16 MFMA GEMM, software-pipelined, dual-stream (blockIdx.z).
// C[M,N] = act(A @ W + bias).  A row-major [M,K]; per-block A = Aq if
// n0 < qsplit else Akv (cross-attention support). W = n_per_mat-wide
// sub-matrices [K, n_per_mat] concatenated along N.
// Block: 128x128 tile, 256 threads (4 waves, 2x2 of 64x64), BK=32.
// ---------------------------------------------------------------------------
__global__ __launch_bounds__(256) void gemm_mfma(
    const float* __restrict__ Aq0, const float* __restrict__ Akv0,
    const float* __restrict__ W0,  const float* __restrict__ bias0, float* __restrict__ C0,
    const float* __restrict__ Aq1, const float* __restrict__ Akv1,
    const float* __restrict__ W1,  const float* __restrict__ bias1, float* __restrict__ C1,
    int qsplit, int K, int N, int n_per_mat, int act)
{
    const int z = blockIdx.z;
    const float* __restrict__ Aq  = z ? Aq1  : Aq0;
    const float* __restrict__ Akv = z ? Akv1 : Akv0;
    const float* __restrict__ Wb  = z ? W1   : W0;
    const float* __restrict__ bias = z ? bias1 : bias0;
    float* __restrict__ C = z ? C1 : C0;

    const int n0 = blockIdx.x * 128;
    const int m0 = blockIdx.y * 128;
    const float* __restrict__ A = (n0 < qsplit) ? Aq : Akv;
    const int sub = n0 / n_per_mat;
    const int nc0 = n0 - sub * n_per_mat;
    const float* __restrict__ W = Wb + (size_t)sub * K * n_per_mat;

    const int tid = threadIdx.x;
    const int lane = tid & 63;
    const int wave = tid >> 6;
    const int wm = (wave & 1) * 64;
    const int wn = (wave >> 1) * 64;

    // LDS planes: [row][k], row stride 40 halves
    __shared__ _Float16 sm[4 * 128 * 40];
    _Float16* Ah = sm;
    _Float16* Al = sm + 128 * 40;
    _Float16* Bh = sm + 2 * 128 * 40;
    _Float16* Bl = sm + 3 * 128 * 40;

    v4f acc[4][4];
    #pragma unroll
    for (int i = 0; i < 4; ++i)
        #pragma unroll
        for (int j = 0; j < 4; ++j)
            acc[i][j] = (v4f){0.f, 0.f, 0.f, 0.f};

    const int ar = tid >> 3;            // A row 0..31 (+32i)
    const int ac = (tid & 7) * 4;       // A k-col (float4)
    const int bn = tid & 127;           // B col
    const int bk0 = (tid >> 7) * 16;    // B k-row base

    const int fm = lane & 15;
    const int fk = (lane >> 4) * 8;

    float4 av[4];
    float bv[16];
    // prologue load (k0 = 0)
    #pragma unroll
    for (int i = 0; i < 4; ++i)
        av[i] = *(const float4*)(A + (size_t)(m0 + ar + 32 * i) * K + ac);
    #pragma unroll
    for (int j = 0; j < 16; ++j)
        bv[j] = W[(size_t)(bk0 + j) * n_per_mat + nc0 + bn];

    for (int k0 = 0; k0 < K; k0 += 32) {
        // ---- issue next iteration's global loads early ----
        float4 av2[4];
        float bv2[16];
        if (k0 + 32 < K) {
            #pragma unroll
            for (int i = 0; i < 4; ++i)
                av2[i] = *(const float4*)(A + (size_t)(m0 + ar + 32 * i) * K + k0 + 32 + ac);
            #pragma unroll
            for (int j = 0; j < 16; ++j)
                bv2[j] = W[(size_t)(k0 + 32 + bk0 + j) * n_per_mat + nc0 + bn];
        }

        __syncthreads();   // previous iteration's fragment reads done

        // ---- convert current + LDS write ----
        #pragma unroll
        for (int i = 0; i < 4; ++i) {
            v2h h0, l0, h1, l1;
            cvt_split(av[i].x, av[i].y, h0, l0);
            cvt_split(av[i].z, av[i].w, h1, l1);
            v4h hh, ll;
            hh[0] = h0[0]; hh[1] = h0[1]; hh[2] = h1[0]; hh[3] = h1[1];
            ll[0] = l0[0]; ll[1] = l0[1]; ll[2] = l1[0]; ll[3] = l1[1];
            *(v4h*)&Ah[(ar + 32 * i) * 40 + ac] = hh;
            *(v4h*)&Al[(ar + 32 * i) * 40 + ac] = ll;
        }
        {
            v8h bha, bhb, bla, blb;
            #pragma unroll
            for (int j = 0; j < 4; ++j) {
                v2h h, l;
                cvt_split(bv[2 * j], bv[2 * j + 1], h, l);
                bha[2 * j] = h[0]; bha[2 * j + 1] = h[1];
                bla[2 * j] = l[0]; bla[2 * j + 1] = l[1];
            }
            #pragma unroll
            for (int j = 0; j < 4; ++j) {
                v2h h, l;
                cvt_split(bv[8 + 2 * j], bv[8 + 2 * j + 1], h, l);
                bhb[2 * j] = h[0]; bhb[2 * j + 1] = h[1];
                blb[2 * j] = l[0]; blb[2 * j + 1] = l[1];
            }
            *(v8h*)&Bh[bn * 40 + bk0] = bha;
            *(v8h*)&Bh[bn * 40 + bk0 + 8] = bhb;
            *(v8h*)&Bl[bn * 40 + bk0] = bla;
            *(v8h*)&Bl[bn * 40 + bk0 + 8] = blb;
        }
        __syncthreads();

        // ---- fragments + MFMA ----
        v8h fah[4], fal[4], fbh[4], fbl[4];
        #pragma unroll
        for (int i = 0; i < 4; ++i) {
            fah[i] = *(v8h*)&Ah[(wm + i * 16 + fm) * 40 + fk];
            fal[i] = *(v8h*)&Al[(wm + i * 16 + fm) * 40 + fk];
        }
        #pragma unroll
        for (int j = 0; j < 4; ++j) {
            fbh[j] = *(v8h*)&Bh[(wn + j * 16 + fm) * 40 + fk];
            fbl[j] = *(v8h*)&Bl[(wn + j * 16 + fm) * 40 + fk];
        }
        #pragma unroll
        for (int i = 0; i < 4; ++i)
            #pragma unroll
            for (int j = 0; j < 4; ++j) {
                acc[i][j] = __builtin_amdgcn_mfma_f32_16x16x32_f16(fah[i], fbh[j], acc[i][j], 0, 0, 0);
                acc[i][j] = __builtin_amdgcn_mfma_f32_16x16x32_f16(fah[i], fbl[j], acc[i][j], 0, 0, 0);
                acc[i][j] = __builtin_amdgcn_mfma_f32_16x16x32_f16(fal[i], fbh[j], acc[i][j], 0, 0, 0);
            }

        #pragma unroll
        for (int i = 0; i < 4; ++i) av[i] = av2[i];
        #pragma unroll
        for (int j = 0; j < 16; ++j) bv[j] = bv2[j];
    }

    // ---- epilogue ----
    const int er = (lane >> 4) * 4;
    const int ec = lane & 15;
    #pragma unroll
    for (int j = 0; j < 4; ++j) {
        const int col = n0 + wn + j * 16 + ec;
        const float bs = bias[col];
        #pragma unroll
        for (int i = 0; i < 4; ++i) {
            #pragma unroll
            for (int r = 0; r < 4; ++r) {
                const int row = m0 + wm + i * 16 + er + r;
                float v = acc[i][j][r] + bs;
                if (act == 1)
                    v = 0.5f * v * (1.0f + erff(v * 0.7071067811865476f));
                C[(size_t)row * N + col] = v;
            }
        }
    }
}

// ---------------------------------------------------------------------------
// MFMA attention, dual-stream (blockIdx.z). qkv [M,2304].
// Block = (b, head, 64-query tile); 4 waves x 16 queries; grid.x = B*H*4.
// Pass 1: S^T = K @ Q^T via split-fp16 MFMA (3 products) over 4 key tiles
//         staged in LDS; scores kept in 64 VGPRs/lane (S^T C-layout puts
//         q on lane&15 -> softmax is per-lane reduce + 2 shfl_xor).
// Pass 2: O = P' @ V via split-fp16 MFMA; P' (unnormalized exp) written to
//         LDS [q][key]; V staged transposed [d][key] (conflict-free b64
//         transpose during fp32->fp16 split). Normalize by 1/rowsum at end.
// LDS: K/V tile buffer unioned (9KB*2) + P (9KB*2) + mask = ~37KB.
// ---------------------------------------------------------------------------
__global__ __launch_bounds__(256) void attn_kernel(
    const float* __restrict__ qkv0, const int* __restrict__ mask0, float* __restrict__ hout0,
    const float* __restrict__ qkv1, const int* __restrict__ mask1, float* __restrict__ hout1)
{
    const float* __restrict__ qkv = blockIdx.z ? qkv1 : qkv0;
    const int* __restrict__ mask = blockIdx.z ? mask1 : mask0;
    float* __restrict__ hout = blockIdx.z ? hout1 : hout0;

    const int blk = blockIdx.x;
    const int qt = blk & 3;           // 4 query tiles of 64
    const int bh = blk >> 2;
    const int head = bh % H;
    const int b = bh / H;
    const int tid = threadIdx.x;
    const int wave = tid >> 6;
    const int lane = tid & 63;
    const int qloc = lane & 15;       // operand m/n index
    const int rg = lane >> 4;         // k-chunk / row-group

    // K tile [key][d] in pass 1; V^T tile [d][key] in pass 2 (union).
    __shared__ _Float16 KVh[64 * 72];
    __shared__ _Float16 KVl[64 * 72];
    // Per-wave P' tiles [q 0..15][key 0..63], row stride 72.
    __shared__ _Float16 Ph[4][16 * 72];
    __shared__ _Float16 Pl[4][16 * 72];
    __shared__ float mpen[256];

    // mask penalties (keys of the KV sequence)
    mpen[tid] = -10000.0f * (1.0f - (float)mask[b * S + tid]);

    // ---- Q fragments (B-operand), registers: lane -> q = qloc, k(d) = ks*32+rg*8+j
    const int qrow = b * S + qt * 64 + wave * 16 + qloc;
    const float* qptr = qkv + (size_t)qrow * 2304 + head * DH + rg * 8;
    v8h qh[2], ql[2];
    #pragma unroll
    for (int ks = 0; ks < 2; ++ks) {
        float4 a = *(const float4*)(qptr + ks * 32);
        float4 c = *(const float4*)(qptr + ks * 32 + 4);
        v2h h, l;
        v8h hh, ll;
        cvt_split(a.x, a.y, h, l); hh[0] = h[0]; hh[1] = h[1]; ll[0] = l[0]; ll[1] = l[1];
        cvt_split(a.z, a.w, h, l); hh[2] = h[0]; hh[3] = h[1]; ll[2] = l[0]; ll[3] = l[1];
        cvt_split(c.x, c.y, h, l); hh[4] = h[0]; hh[5] = h[1]; ll[4] = l[0]; ll[5] = l[1];
        cvt_split(c.z, c.w, h, l); hh[6] = h[0]; hh[7] = h[1]; ll[6] = l[0]; ll[7] = l[1];
        qh[ks] = hh; ql[ks] = ll;
    }

    v4f acc_s[16];
    #pragma unroll
    for (int i = 0; i < 16; ++i) acc_s[i] = (v4f){0.f, 0.f, 0.f, 0.f};

    const float* kbase = qkv + 768 + head * DH;
    const float* vbase = qkv + 1536 + head * DH;

    // ---- pass 1: scores S^T (A = K tile, B = Q) ----
    const int skey = tid & 63;           // staging: key row
    const int sseg = (tid >> 6) * 16;    // staging: d segment
    #pragma unroll
    for (int t = 0; t < 4; ++t) {
        __syncthreads();
        {
            const float* src = kbase + (size_t)(b * S + t * 64 + skey) * 2304 + sseg;
            float4 a = ((const float4*)src)[0];
            float4 c = ((const float4*)src)[1];
            float4 e = ((const float4*)src)[2];
            float4 f = ((const float4*)src)[3];
            v2h h, l;
            v8h hA, lA, hB, lB;
            cvt_split(a.x, a.y, h, l); hA[0] = h[0]; hA[1] = h[1]; lA[0] = l[0]; lA[1] = l[1];
            cvt_split(a.z, a.w, h, l); hA[2] = h[0]; hA[3] = h[1]; lA[2] = l[0]; lA[3] = l[1];
            cvt_split(c.x, c.y, h, l); hA[4] = h[0]; hA[5] = h[1]; lA[4] = l[0]; lA[5] = l[1];
            cvt_split(c.z, c.w, h, l); hA[6] = h[0]; hA[7] = h[1]; lA[6] = l[0]; lA[7] = l[1];
            cvt_split(e.x, e.y, h, l); hB[0] = h[0]; hB[1] = h[1]; lB[0] = l[0]; lB[1] = l[1];
            cvt_split(e.z, e.w, h, l); hB[2] = h[0]; hB[3] = h[1]; lB[2] = l[0]; lB[3] = l[1];
            cvt_split(f.x, f.y, h, l); hB[4] = h[0]; hB[5] = h[1]; lB[4] = l[0]; lB[5] = l[1];
            cvt_split(f.z, f.w, h, l); hB[6] = h[0]; hB[7] = h[1]; lB[6] = l[0]; lB[7] = l[1];
            *(v8h*)&KVh[skey * 72 + sseg] = hA;
            *(v8h*)&KVh[skey * 72 + sseg + 8] = hB;
            *(v8h*)&KVl[skey * 72 + sseg] = lA;
            *(v8h*)&KVl[skey * 72 + sseg + 8] = lB;
        }
        __syncthreads();
        #pragma unroll
        for (int sub = 0; sub < 4; ++sub) {
            v8h kh[2], kl[2];
            #pragma unroll
            for (int ks = 0; ks < 2; ++ks) {
                kh[ks] = *(v8h*)&KVh[(sub * 16 + qloc) * 72 + ks * 32 + rg * 8];
                kl[ks] = *(v8h*)&KVl[(sub * 16 + qloc) * 72 + ks * 32 + rg * 8];
            }
            v4f acc = acc_s[t * 4 + sub];
            #pragma unroll
            for (int ks = 0; ks < 2; ++ks) {
                acc = __builtin_amdgcn_mfma_f32_16x16x32_f16(kh[ks], qh[ks], acc, 0, 0, 0);
                acc = __builtin_amdgcn_mfma_f32_16x16x32_f16(kh[ks], ql[ks], acc, 0, 0, 0);
                acc = __builtin_amdgcn_mfma_f32_16x16x32_f16(kl[ks], qh[ks], acc, 0, 0, 0);
            }
            acc_s[t * 4 + sub] = acc;
        }
    }

    // ---- softmax (q = qloc; keys = mt*16 + rg*4 + r across 4 rg groups) ----
    float mx = -3.0e38f;
    #pragma unroll
    for (int mt = 0; mt < 16; ++mt) {
        float4 mp = *(const float4*)&mpen[mt * 16 + rg * 4];
        v4f s = acc_s[mt];
        s[0] = s[0] * 0.125f + mp.x;
        s[1] = s[1] * 0.125f + mp.y;
        s[2] = s[2] * 0.125f + mp.z;
        s[3] = s[3] * 0.125f + mp.w;
        acc_s[mt] = s;
        mx = fmaxf(mx, fmaxf(fmaxf(s[0], s[1]), fmaxf(s[2], s[3])));
    }
    mx = fmaxf(mx, __shfl_xor(mx, 16, 64));
    mx = fmaxf(mx, __shfl_xor(mx, 32, 64));
    float sum = 0.f;
    #pragma unroll
    for (int mt = 0; mt < 16; ++mt) {
        v4f s = acc_s[mt];
        s[0] = __expf(s[0] - mx);
        s[1] = __expf(s[1] - mx);
        s[2] = __expf(s[2] - mx);
        s[3] = __expf(s[3] - mx);
        acc_s[mt] = s;
        sum += (s[0] + s[1]) + (s[2] + s[3]);
    }
    sum += __shfl_xor(sum, 16, 64);
    sum += __shfl_xor(sum, 32, 64);
    const float inv = 1.0f / sum;

    // ---- pass 2: O = P' @ V (A = P', B = V^T) ----
    v4f acc_o[4];
    #pragma unroll
    for (int j = 0; j < 4; ++j) acc_o[j] = (v4f){0.f, 0.f, 0.f, 0.f};

    const int vk4 = (tid & 15) * 4;   // staging: key group
    const int vd4 = (tid >> 4) * 4;   // staging: d group
    #pragma unroll
    for (int t = 0; t < 4; ++t) {
        __syncthreads();   // previous tile's LDS reads done
        // write this wave's P' tile: [q = qloc][key = sub*16 + rg*4 + r]
        #pragma unroll
        for (int sub = 0; sub < 4; ++sub) {
            v4f p = acc_s[t * 4 + sub];
            v2h h01, l01, h23, l23;
            cvt_split(p[0], p[1], h01, l01);
            cvt_split(p[2], p[3], h23, l23);
            *(v2h*)&Ph[wave][qloc * 72 + sub * 16 + rg * 4] = h01;
            *(v2h*)&Ph[wave][qloc * 72 + sub * 16 + rg * 4 + 2] = h23;
            *(v2h*)&Pl[wave][qloc * 72 + sub * 16 + rg * 4] = l01;
            *(v2h*)&Pl[wave][qloc * 72 + sub * 16 + rg * 4 + 2] = l23;
        }
        // stage V^T tile: read V[key][d] coalesced, write [d][key]
        {
            v4h rh[4], rl[4];
            #pragma unroll
            for (int i = 0; i < 4; ++i) {
                const float4 vv = *(const float4*)(vbase + (size_t)(b * S + t * 64 + vk4 + i) * 2304 + vd4);
                v2h h0, l0, h1, l1;
                cvt_split(vv.x, vv.y, h0, l0);
                cvt_split(vv.z, vv.w, h1, l1);
                rh[0][i] = h0[0]; rh[1][i] = h0[1]; rh[2][i] = h1[0]; rh[3][i] = h1[1];
                rl[0][i] = l0[0]; rl[1][i] = l0[1]; rl[2][i] = l1[0]; rl[3][i] = l1[1];
            }
            #pragma unroll
            for (int j = 0; j < 4; ++j) {
                *(v4h*)&KVh[(vd4 + j) * 72 + vk4] = rh[j];
                *(v4h*)&KVl[(vd4 + j) * 72 + vk4] = rl[j];
            }
        }
        __syncthreads();
        v8h pah[2], pal[2];
        #pragma unroll
        for (int ks = 0; ks < 2; ++ks) {
            pah[ks] = *(v8h*)&Ph[wave][qloc * 72 + ks * 32 + rg * 8];
            pal[ks] = *(v8h*)&Pl[wave][qloc * 72 + ks * 32 + rg * 8];
        }
        #pragma unroll
        for (int j = 0; j < 4; ++j) {
            v4f acc = acc_o[j];
            #pragma unroll
            for (int ks = 0; ks < 2; ++ks) {
                v8h vbh = *(v8h*)&KVh[(j * 16 + qloc) * 72 + ks * 32 + rg * 8];
                v8h vbl = *(v8h*)&KVl[(j * 16 + qloc) * 72 + ks * 32 + rg * 8];
                acc = __builtin_amdgcn_mfma_f32_16x16x32_f16(pah[ks], vbh, acc, 0, 0, 0);
                acc = __builtin_amdgcn_mfma_f32_16x16x32_f16(pah[ks], vbl, acc, 0, 0, 0);
                acc = __builtin_amdgcn_mfma_f32_16x16x32_f16(pal[ks], vbh, acc, 0, 0, 0);
            }
            acc_o[j] = acc;
        }
    }

    // ---- epilogue: normalize + store. C-layout: row q = rg*4 + r, col d = j*16 + qloc
    #pragma unroll
    for (int r = 0; r < 4; ++r) {
        const float invr = __shfl(inv, rg * 4 + r, 64);
        const size_t row = (size_t)(b * S + qt * 64 + wave * 16 + rg * 4 + r);
        #pragma unroll
        for (int j = 0; j < 4; ++j)
            hout[row * D + head * DH + j * 16 + qloc] = acc_o[j][r] * invr;
    }
}

// ---------------------------------------------------------------------------
// Residual + LayerNorm (in-place), dual-stream via blockIdx.y.
// ---------------------------------------------------------------------------
__global__ __launch_bounds__(256) void ln_res_kernel(
    float* __restrict__ x0, const float* __restrict__ h0,
    const float* __restrict__ g0, const float* __restrict__ bb0,
    float* __restrict__ x1, const float* __restrict__ h1,
    const float* __restrict__ g1, const float* __restrict__ bb1)
{
    float* __restrict__ x = blockIdx.y ? x1 : x0;
    const float* __restrict__ h = blockIdx.y ? h1 : h0;
    const float* __restrict__ g = blockIdx.y ? g1 : g0;
    const float* __restrict__ bb = blockIdx.y ? bb1 : bb0;

    const int row = blockIdx.x;
    const int tid = threadIdx.x;
    const int wave = tid >> 6;
    const int lane = tid & 63;
    __shared__ float red[4];

    float v[3];
    #pragma unroll
    for (int i = 0; i < 3; ++i) {
        int c = tid + 256 * i;
        v[i] = x[(size_t)row * D + c] + h[(size_t)row * D + c];
    }
    float s = v[0] + v[1] + v[2];
    #pragma unroll
    for (int o = 32; o > 0; o >>= 1) s += __shfl_xor(s, o, 64);
    if (lane == 0) red[wave] = s;
    __syncthreads();
    const float mean = (red[0] + red[1] + red[2] + red[3]) * (1.0f / 768.0f);

    float qs = 0.f;
    #pragma unroll
    for (int i = 0; i < 3; ++i) { float d = v[i] - mean; qs += d * d; }
    #pragma unroll
    for (int o = 32; o > 0; o >>= 1) qs += __shfl_xor(qs, o, 64);
    __syncthreads();
    if (lane == 0) red[wave] = qs;
    __syncthreads();
    const float var = (red[0] + red[1] + red[2] + red[3]) * (1.0f / 768.0f);
    const float rstd = rsqrtf(var + 1e-12f);

    #pragma unroll
    for (int i = 0; i < 3; ++i) {
        int c = tid + 256 * i;
        x[(size_t)row * D + c] = (v[i] - mean) * rstd * g[c] + bb[c];
    }
}

// ---------------------------------------------------------------------------
// Host launcher
// ---------------------------------------------------------------------------
extern "C" void kernel_launch(void* const* d_in, const int* in_sizes, int n_in,
                              void* d_out, int out_size, void* d_ws, size_t ws_size,
                              hipStream_t stream)
{
    const float* x    = (const float*)d_in[0];
    const float* y    = (const float*)d_in[1];
    const int*   xm   = (const int*)d_in[2];
    const int*   ym   = (const int*)d_in[3];
    const float* ax_w = (const float*)d_in[4];
    const float* ax_b = (const float*)d_in[5];
    const float* cx_w = (const float*)d_in[6];
    const float* cx_b = (const float*)d_in[7];
    const float* fx_w1 = (const float*)d_in[8];
    const float* fx_b1 = (const float*)d_in[9];
    const float* fx_w2 = (const float*)d_in[10];
    const float* fx_b2 = (const float*)d_in[11];
    const float* ay_w = (const float*)d_in[12];
    const float* ay_b = (const float*)d_in[13];
    const float* cy_w = (const float*)d_in[14];
    const float* cy_b = (const float*)d_in[15];
    const float* fy_w1 = (const float*)d_in[16];
    const float* fy_b1 = (const float*)d_in[17];
    const float* fy_w2 = (const float*)d_in[18];
    const float* fy_b2 = (const float*)d_in[19];
    const float* lnx_g = (const float*)d_in[20];
    const float* lnx_b = (const float*)d_in[21];
    const float* lny_g = (const float*)d_in[22];
    const float* lny_b = (const float*)d_in[23];

    float* xc = (float*)d_out;
    float* yc = xc + (size_t)M * D;

    // Workspace layout. Big (merged) path needs 2 qkv/ffn-mid buffers + 2 hbufs.
    const size_t need = ((size_t)2 * M * D4 + (size_t)2 * M * D) * sizeof(float);
    const bool big = ws_size >= need;
    float* ws0 = (float*)d_ws;
    float* qkvx = ws0;
    float* qkvy = big ? ws0 + (size_t)M * D4 : ws0;
    float* hbx = ws0 + (big ? (size_t)2 * M * D4 : (size_t)M * D4);
    float* hby = big ? hbx + (size_t)M * D : hbx;

    (void)hipMemcpyAsync(xc, x, (size_t)M * D * sizeof(float), hipMemcpyDeviceToDevice, stream);
    (void)hipMemcpyAsync(yc, y, (size_t)M * D * sizeof(float), hipMemcpyDeviceToDevice, stream);

    const dim3 blk(256);

    auto qkv_gemm = [&](const float* aq0, const float* akv0, const float* w0, const float* bi0, float* c0,
                        const float* aq1, const float* akv1, const float* w1, const float* bi1, float* c1,
                        int nz) {
        gemm_mfma<<<dim3(2304 / 128, M / 128, nz), blk, 0, stream>>>(
            aq0, akv0, w0, bi0, c0, aq1, akv1, w1, bi1, c1, 768, D, 2304, 768, 0);
    };
    auto ffn1_gemm = [&](const float* a0, const float* w0, const float* bi0, float* c0,
                         const float* a1, const float* w1, const float* bi1, float* c1, int nz) {
        gemm_mfma<<<dim3(D4 / 128, M / 128, nz), blk, 0, stream>>>(
            a0, a0, w0, bi0, c0, a1, a1, w1, bi1, c1, 0, D, D4, D4, 1);
    };
    auto ffn2_gemm = [&](const float* a0, const float* w0, const float* bi0, float* c0,
                         const float* a1, const float* w1, const float* bi1, float* c1, int nz) {
        gemm_mfma<<<dim3(D / 128, M / 128, nz), blk, 0, stream>>>(
            a0, a0, w0, bi0, c0, a1, a1, w1, bi1, c1, 0, D4, D, D, 0);
    };
    auto attn = [&](const float* q0, const int* m0_, float* h0,
                    const float* q1, const int* m1_, float* h1, int nz) {
        attn_kernel<<<dim3(B * H * 4, 1, nz), blk, 0, stream>>>(q0, m0_, h0, q1, m1_, h1);
    };
    auto ln = [&](float* x0, const float* h0, const float* g0, const float* b0,
                  float* x1, const float* h1, const float* g1, const float* b1, int ny) {
        ln_res_kernel<<<dim3(M, ny), blk, 0, stream>>>(x0, h0, g0, b0, x1, h1, g1, b1);
    };

    for (int l = 0; l < L; ++l) {
        const size_t wo = (size_t)l * 3 * D * D;
        const size_t bo = (size_t)l * 3 * D;
        const size_t f1o = (size_t)l * D * D4;
        const size_t f1bo = (size_t)l * D4;
        const size_t f2o = (size_t)l * D4 * D;
        const size_t f2bo = (size_t)l * D;

        if (big) {
            // self-attention x & y merged
            qkv_gemm(xc, xc, ax_w + wo, ax_b + bo, qkvx,
                     yc, yc, ay_w + wo, ay_b + bo, qkvy, 2);
            attn(qkvx, xm, hbx, qkvy, ym, hby, 2);
            ln(xc, hbx, lnx_g, lnx_b, yc, hby, lny_g, lny_b, 2);
            // cross-x (q from xc, kv from yc, mask ym)
            qkv_gemm(xc, yc, cx_w + wo, cx_b + bo, qkvx,
                     xc, yc, cx_w + wo, cx_b + bo, qkvx, 1);
            attn(qkvx, ym, hbx, qkvx, ym, hbx, 1);
            ln(xc, hbx, lnx_g + D, lnx_b + D, xc, hbx, lnx_g + D, lnx_b + D, 1);
            // cross-y (q from yc, kv from updated xc, mask xm)
            qkv_gemm(yc, xc, cy_w + wo, cy_b + bo, qkvy,
                     yc, xc, cy_w + wo, cy_b + bo, qkvy, 1);
            attn(qkvy, xm, hby, qkvy, xm, hby, 1);
            ln(yc, hby, lny_g + D, lny_b + D, yc, hby, lny_g + D, lny_b + D, 1);
            // FFN merged
            ffn1_gemm(xc, fx_w1 + f1o, fx_b1 + f1bo, qkvx,
                      yc, fy_w1 + f1o, fy_b1 + f1bo, qkvy, 2);
            ffn2_gemm(qkvx, fx_w2 + f2o, fx_b2 + f2bo, hbx,
                      qkvy, fy_w2 + f2o, fy_b2 + f2bo, hby, 2);
            ln(xc, hbx, lnx_g + 2 * D, lnx_b + 2 * D,
               yc, hby, lny_g + 2 * D, lny_b + 2 * D, 2);
        } else {
            // sequential fallback (aliased buffers)
            qkv_gemm(xc, xc, ax_w + wo, ax_b + bo, qkvx, xc, xc, ax_w + wo, ax_b + bo, qkvx, 1);
            attn(qkvx, xm, hbx, qkvx, xm, hbx, 1);
            ln(xc, hbx, lnx_g, lnx_b, xc, hbx, lnx_g, lnx_b, 1);
            qkv_gemm(yc, yc, ay_w + wo, ay_b + bo, qkvy, yc, yc, ay_w + wo, ay_b + bo, qkvy, 1);
            attn(qkvy, ym, hby, qkvy, ym, hby, 1);
            ln(yc, hby, lny_g, lny_b, yc, hby, lny_g, lny_b, 1);
            qkv_gemm(xc, yc, cx_w + wo, cx_b + bo, qkvx, xc, yc, cx_w + wo, cx_b + bo, qkvx, 1);
            attn(qkvx, ym, hbx, qkvx, ym, hbx, 1);
            ln(xc, hbx, lnx_g + D, lnx_b + D, xc, hbx, lnx_g + D, lnx_b + D, 1);
            qkv_gemm(yc, xc, cy_w + wo, cy_b + bo, qkvy, yc, xc, cy_w + wo, cy_b + bo, qkvy, 1);
            attn(qkvy, xm, hby, qkvy, xm, hby, 1);
            ln(yc, hby, lny_g + D, lny_b + D, yc, hby, lny_g + D, lny_b + D, 1);
            ffn1_gemm(xc, fx_w1 + f1o, fx_b1 + f1bo, qkvx, xc, fx_w1 + f1o, fx_b1 + f1bo, qkvx, 1);
            ffn2_gemm(qkvx, fx_w2 + f2o, fx_b2 + f2bo, hbx, qkvx, fx_w2 + f2o, fx_b2 + f2bo, hbx, 1);
            ln(xc, hbx, lnx_g + 2 * D, lnx_b + 2 * D, xc, hbx, lnx_g + 2 * D, lnx_b + 2 * D, 1);
            ffn1_gemm(yc, fy_w1 + f1o, fy_b1 + f1bo, qkvy, yc, fy_w1 + f1o, fy_b1 + f1bo, qkvy, 1);
            ffn2_gemm(qkvy, fy_w2 + f2o, fy_b2 + f2bo, hby, qkvy, fy_w2 + f2o, fy_b2 + f2bo, hby, 1);
            ln(yc, hby, lny_g + 2 * D, lny_b + 2 * D, yc, hby, lny_g + 2 * D, lny_b + 2 * D, 1);
        }
    }
}

// Round 2
// 3026.400 us; speedup vs baseline: 1.8214x; 1.2320x over previous
//
#include <hip/hip_runtime.h>
#include <math.h>

// Problem constants
constexpr int D = 768;
constexpr int H = 12;
constexpr int L = 6;
constexpr int B = 8;
constexpr int S = 256;
constexpr int DH = 64;      // D/H
constexpr int M = B * S;    // 2048 rows
constexpr int D4 = 4 * D;   // 3072

typedef _Float16 v2h __attribute__((ext_vector_type(2)));
typedef _Float16 v4h __attribute__((ext_vector_type(4)));
typedef _Float16 v8h __attribute__((ext_vector_type(8)));
typedef __fp16 f16x2 __attribute__((ext_vector_type(2)));
typedef float v4f __attribute__((ext_vector_type(4)));

// fp32 -> hi/lo fp16 split (Markidis). hi = rtz(x); lo = rtz(x - hi).
__device__ inline void cvt_split(float x, float y, v2h& hi, v2h& lo) {
    f16x2 h = __builtin_amdgcn_cvt_pkrtz(x, y);
    float rx = x - (float)h[0];
    float ry = y - (float)h[1];
    f16x2 l = __builtin_amdgcn_cvt_pkrtz(rx, ry);
    hi = __builtin_bit_cast(v2h, h);
    lo = __builtin_bit_cast(v2h, l);
}

// ---------------------------------------------------------------------------
// Split-fp16 MFMA GEMM, software-pipelined, dual-stream (blockIdx.z).
// C[M,N] = act(A @ W + bias).  A row-major [M,Kstride]; per-block A = Aq if
// n0 < qsplit else Akv (cross-attention support). W = n_per_mat-wide
// sub-matrices [Kstride, n_per_mat] concatenated along N.
// Split-K: grid.x = nblks * nparts; kpart = blockIdx.x / nblks selects a
// kchunk-length K slice; atomic=1 -> epilogue atomicAdd (C pre-zeroed),
// bias applied by part 0 only.
// Block: 128x128 tile, 256 threads (4 waves, 2x2 of 64x64), BK=32.
// ---------------------------------------------------------------------------
__global__ __launch_bounds__(256) void gemm_mfma(
    const float* __restrict__ Aq0, const float* __restrict__ Akv0,
    const float* __restrict__ W0,  const float* __restrict__ bias0, float* __restrict__ C0,
    const float* __restrict__ Aq1, const float* __restrict__ Akv1,
    const float* __restrict__ W1,  const float* __restrict__ bias1, float* __restrict__ C1,
    int qsplit, int Kstride, int kchunk, int N, int n_per_mat, int nblks, int act, int atomic)
{
    const int z = blockIdx.z;
    const float* __restrict__ Aq  = z ? Aq1  : Aq0;
    const float* __restrict__ Akv = z ? Akv1 : Akv0;
    const float* __restrict__ Wb  = z ? W1   : W0;
    const float* __restrict__ biasz = z ? bias1 : bias0;
    float* __restrict__ C = z ? C1 : C0;

    const int bx = blockIdx.x;
    const int nb = bx % nblks;
    const int kpart = bx / nblks;
    const int n0 = nb * 128;
    const int m0 = blockIdx.y * 128;
    const float* __restrict__ A = ((n0 < qsplit) ? Aq : Akv) + (size_t)kpart * kchunk;
    const int sub = n0 / n_per_mat;
    const int nc0 = n0 - sub * n_per_mat;
    const float* __restrict__ W = Wb + (size_t)sub * Kstride * n_per_mat
                                     + (size_t)kpart * kchunk * n_per_mat;
    const float* __restrict__ bias = (kpart == 0) ? biasz : nullptr;

    const int tid = threadIdx.x;
    const int lane = tid & 63;
    const int wave = tid >> 6;
    const int wm = (wave & 1) * 64;
    const int wn = (wave >> 1) * 64;

    // LDS planes: [row][k], row stride 40 halves
    __shared__ _Float16 sm[4 * 128 * 40];
    _Float16* Ah = sm;
    _Float16* Al = sm + 128 * 40;
    _Float16* Bh = sm + 2 * 128 * 40;
    _Float16* Bl = sm + 3 * 128 * 40;

    v4f acc[4][4];
    #pragma unroll
    for (int i = 0; i < 4; ++i)
        #pragma unroll
        for (int j = 0; j < 4; ++j)
            acc[i][j] = (v4f){0.f, 0.f, 0.f, 0.f};

    const int ar = tid >> 3;            // A row 0..31 (+32i)
    const int ac = (tid & 7) * 4;       // A k-col (float4)
    const int bn = tid & 127;           // B col
    const int bk0 = (tid >> 7) * 16;    // B k-row base

    const int fm = lane & 15;
    const int fk = (lane >> 4) * 8;

    float4 av[4], av2[4];
    float bv[16], bv2[16];
    // prologue load (k0 = 0)
    #pragma unroll
    for (int i = 0; i < 4; ++i)
        av[i] = *(const float4*)(A + (size_t)(m0 + ar + 32 * i) * Kstride + ac);
    #pragma unroll
    for (int j = 0; j < 16; ++j)
        bv[j] = W[(size_t)(bk0 + j) * n_per_mat + nc0 + bn];

    for (int k0 = 0; k0 < kchunk; k0 += 32) {
        __syncthreads();   // previous iteration's fragment reads done

        // ---- convert current + LDS write ----
        #pragma unroll
        for (int i = 0; i < 4; ++i) {
            v2h h0, l0, h1, l1;
            cvt_split(av[i].x, av[i].y, h0, l0);
            cvt_split(av[i].z, av[i].w, h1, l1);
            v4h hh, ll;
            hh[0] = h0[0]; hh[1] = h0[1]; hh[2] = h1[0]; hh[3] = h1[1];
            ll[0] = l0[0]; ll[1] = l0[1]; ll[2] = l1[0]; ll[3] = l1[1];
            *(v4h*)&Ah[(ar + 32 * i) * 40 + ac] = hh;
            *(v4h*)&Al[(ar + 32 * i) * 40 + ac] = ll;
        }
        {
            v8h bha, bhb, bla, blb;
            #pragma unroll
            for (int j = 0; j < 4; ++j) {
                v2h h, l;
                cvt_split(bv[2 * j], bv[2 * j + 1], h, l);
                bha[2 * j] = h[0]; bha[2 * j + 1] = h[1];
                bla[2 * j] = l[0]; bla[2 * j + 1] = l[1];
            }
            #pragma unroll
            for (int j = 0; j < 4; ++j) {
                v2h h, l;
                cvt_split(bv[8 + 2 * j], bv[8 + 2 * j + 1], h, l);
                bhb[2 * j] = h[0]; bhb[2 * j + 1] = h[1];
                blb[2 * j] = l[0]; blb[2 * j + 1] = l[1];
            }
            *(v8h*)&Bh[bn * 40 + bk0] = bha;
            *(v8h*)&Bh[bn * 40 + bk0 + 8] = bhb;
            *(v8h*)&Bl[bn * 40 + bk0] = bla;
            *(v8h*)&Bl[bn * 40 + bk0 + 8] = blb;
        }
        __syncthreads();

        // ---- issue next iteration's global loads AFTER the barrier so they
        //      overlap the fragment reads + MFMA (drained at next barrier) ----
        if (k0 + 32 < kchunk) {
            #pragma unroll
            for (int i = 0; i < 4; ++i)
                av2[i] = *(const float4*)(A + (size_t)(m0 + ar + 32 * i) * Kstride + k0 + 32 + ac);
            #pragma unroll
            for (int j = 0; j < 16; ++j)
                bv2[j] = W[(size_t)(k0 + 32 + bk0 + j) * n_per_mat + nc0 + bn];
        }

        // ---- fragments + MFMA ----
        v8h fah[4], fal[4], fbh[4], fbl[4];
        #pragma unroll
        for (int i = 0; i < 4; ++i) {
            fah[i] = *(v8h*)&Ah[(wm + i * 16 + fm) * 40 + fk];
            fal[i] = *(v8h*)&Al[(wm + i * 16 + fm) * 40 + fk];
        }
        #pragma unroll
        for (int j = 0; j < 4; ++j) {
            fbh[j] = *(v8h*)&Bh[(wn + j * 16 + fm) * 40 + fk];
            fbl[j] = *(v8h*)&Bl[(wn + j * 16 + fm) * 40 + fk];
        }
        #pragma unroll
        for (int i = 0; i < 4; ++i)
            #pragma unroll
            for (int j = 0; j < 4; ++j) {
                acc[i][j] = __builtin_amdgcn_mfma_f32_16x16x32_f16(fah[i], fbh[j], acc[i][j], 0, 0, 0);
                acc[i][j] = __builtin_amdgcn_mfma_f32_16x16x32_f16(fah[i], fbl[j], acc[i][j], 0, 0, 0);
                acc[i][j] = __builtin_amdgcn_mfma_f32_16x16x32_f16(fal[i], fbh[j], acc[i][j], 0, 0, 0);
            }

        #pragma unroll
        for (int i = 0; i < 4; ++i) av[i] = av2[i];
        #pragma unroll
        for (int j = 0; j < 16; ++j) bv[j] = bv2[j];
    }

    // ---- epilogue ----
    const int er = (lane >> 4) * 4;
    const int ec = lane & 15;
    #pragma unroll
    for (int j = 0; j < 4; ++j) {
        const int col = n0 + wn + j * 16 + ec;
        const float bs = bias ? bias[col] : 0.0f;
        #pragma unroll
        for (int i = 0; i < 4; ++i) {
            #pragma unroll
            for (int r = 0; r < 4; ++r) {
                const int row = m0 + wm + i * 16 + er + r;
                float v = acc[i][j][r] + bs;
                if (act == 1)
                    v = 0.5f * v * (1.0f + erff(v * 0.7071067811865476f));
                if (atomic)
                    atomicAdd(&C[(size_t)row * N + col], v);
                else
                    C[(size_t)row * N + col] = v;
            }
        }
    }
}

// ---------------------------------------------------------------------------
// MFMA attention, dual-stream (blockIdx.z). qkv [M,2304].
// Block = (b, head, 64-query tile); 4 waves x 16 queries; grid.x = B*H*4.
// ---------------------------------------------------------------------------
__global__ __launch_bounds__(256) void attn_kernel(
    const float* __restrict__ qkv0, const int* __restrict__ mask0, float* __restrict__ hout0,
    const float* __restrict__ qkv1, const int* __restrict__ mask1, float* __restrict__ hout1)
{
    const float* __restrict__ qkv = blockIdx.z ? qkv1 : qkv0;
    const int* __restrict__ mask = blockIdx.z ? mask1 : mask0;
    float* __restrict__ hout = blockIdx.z ? hout1 : hout0;

    const int blk = blockIdx.x;
    const int qt = blk & 3;           // 4 query tiles of 64
    const int bh = blk >> 2;
    const int head = bh % H;
    const int b = bh / H;
    const int tid = threadIdx.x;
    const int wave = tid >> 6;
    const int lane = tid & 63;
    const int qloc = lane & 15;       // operand m/n index
    const int rg = lane >> 4;         // k-chunk / row-group

    // K tile [key][d] in pass 1; V^T tile [d][key] in pass 2 (union).
    __shared__ _Float16 KVh[64 * 72];
    __shared__ _Float16 KVl[64 * 72];
    // Per-wave P' tiles [q 0..15][key 0..63], row stride 72.
    __shared__ _Float16 Ph[4][16 * 72];
    __shared__ _Float16 Pl[4][16 * 72];
    __shared__ float mpen[256];

    // mask penalties (keys of the KV sequence)
    mpen[tid] = -10000.0f * (1.0f - (float)mask[b * S + tid]);

    // ---- Q fragments (B-operand), registers: lane -> q = qloc, k(d) = ks*32+rg*8+j
    const int qrow = b * S + qt * 64 + wave * 16 + qloc;
    const float* qptr = qkv + (size_t)qrow * 2304 + head * DH + rg * 8;
    v8h qh[2], ql[2];
    #pragma unroll
    for (int ks = 0; ks < 2; ++ks) {
        float4 a = *(const float4*)(qptr + ks * 32);
        float4 c = *(const float4*)(qptr + ks * 32 + 4);
        v2h h, l;
        v8h hh, ll;
        cvt_split(a.x, a.y, h, l); hh[0] = h[0]; hh[1] = h[1]; ll[0] = l[0]; ll[1] = l[1];
        cvt_split(a.z, a.w, h, l); hh[2] = h[0]; hh[3] = h[1]; ll[2] = l[0]; ll[3] = l[1];
        cvt_split(c.x, c.y, h, l); hh[4] = h[0]; hh[5] = h[1]; ll[4] = l[0]; ll[5] = l[1];
        cvt_split(c.z, c.w, h, l); hh[6] = h[0]; hh[7] = h[1]; ll[6] = l[0]; ll[7] = l[1];
        qh[ks] = hh; ql[ks] = ll;
    }

    v4f acc_s[16];
    #pragma unroll
    for (int i = 0; i < 16; ++i) acc_s[i] = (v4f){0.f, 0.f, 0.f, 0.f};

    const float* kbase = qkv + 768 + head * DH;
    const float* vbase = qkv + 1536 + head * DH;

    // ---- pass 1: scores S^T (A = K tile, B = Q) ----
    const int skey = tid & 63;           // staging: key row
    const int sseg = (tid >> 6) * 16;    // staging: d segment
    #pragma unroll
    for (int t = 0; t < 4; ++t) {
        __syncthreads();
        {
            const float* src = kbase + (size_t)(b * S + t * 64 + skey) * 2304 + sseg;
            float4 a = ((const float4*)src)[0];
            float4 c = ((const float4*)src)[1];
            float4 e = ((const float4*)src)[2];
            float4 f = ((const float4*)src)[3];
            v2h h, l;
            v8h hA, lA, hB, lB;
            cvt_split(a.x, a.y, h, l); hA[0] = h[0]; hA[1] = h[1]; lA[0] = l[0]; lA[1] = l[1];
            cvt_split(a.z, a.w, h, l); hA[2] = h[0]; hA[3] = h[1]; lA[2] = l[0]; lA[3] = l[1];
            cvt_split(c.x, c.y, h, l); hA[4] = h[0]; hA[5] = h[1]; lA[4] = l[0]; lA[5] = l[1];
            cvt_split(c.z, c.w, h, l); hA[6] = h[0]; hA[7] = h[1]; lA[6] = l[0]; lA[7] = l[1];
            cvt_split(e.x, e.y, h, l); hB[0] = h[0]; hB[1] = h[1]; lB[0] = l[0]; lB[1] = l[1];
            cvt_split(e.z, e.w, h, l); hB[2] = h[0]; hB[3] = h[1]; lB[2] = l[0]; lB[3] = l[1];
            cvt_split(f.x, f.y, h, l); hB[4] = h[0]; hB[5] = h[1]; lB[4] = l[0]; lB[5] = l[1];
            cvt_split(f.z, f.w, h, l); hB[6] = h[0]; hB[7] = h[1]; lB[6] = l[0]; lB[7] = l[1];
            *(v8h*)&KVh[skey * 72 + sseg] = hA;
            *(v8h*)&KVh[skey * 72 + sseg + 8] = hB;
            *(v8h*)&KVl[skey * 72 + sseg] = lA;
            *(v8h*)&KVl[skey * 72 + sseg + 8] = lB;
        }
        __syncthreads();
        #pragma unroll
        for (int sub = 0; sub < 4; ++sub) {
            v8h kh[2], kl[2];
            #pragma unroll
            for (int ks = 0; ks < 2; ++ks) {
                kh[ks] = *(v8h*)&KVh[(sub * 16 + qloc) * 72 + ks * 32 + rg * 8];
                kl[ks] = *(v8h*)&KVl[(sub * 16 + qloc) * 72 + ks * 32 + rg * 8];
            }
            v4f acc = acc_s[t * 4 + sub];
            #pragma unroll
            for (int ks = 0; ks < 2; ++ks) {
                acc = __builtin_amdgcn_mfma_f32_16x16x32_f16(kh[ks], qh[ks], acc, 0, 0, 0);
                acc = __builtin_amdgcn_mfma_f32_16x16x32_f16(kh[ks], ql[ks], acc, 0, 0, 0);
                acc = __builtin_amdgcn_mfma_f32_16x16x32_f16(kl[ks], qh[ks], acc, 0, 0, 0);
            }
            acc_s[t * 4 + sub] = acc;
        }
    }

    // ---- softmax (q = qloc; keys = mt*16 + rg*4 + r across 4 rg groups) ----
    float mx = -3.0e38f;
    #pragma unroll
    for (int mt = 0; mt < 16; ++mt) {
        float4 mp = *(const float4*)&mpen[mt * 16 + rg * 4];
        v4f s = acc_s[mt];
        s[0] = s[0] * 0.125f + mp.x;
        s[1] = s[1] * 0.125f + mp.y;
        s[2] = s[2] * 0.125f + mp.z;
        s[3] = s[3] * 0.125f + mp.w;
        acc_s[mt] = s;
        mx = fmaxf(mx, fmaxf(fmaxf(s[0], s[1]), fmaxf(s[2], s[3])));
    }
    mx = fmaxf(mx, __shfl_xor(mx, 16, 64));
    mx = fmaxf(mx, __shfl_xor(mx, 32, 64));
    float sum = 0.f;
    #pragma unroll
    for (int mt = 0; mt < 16; ++mt) {
        v4f s = acc_s[mt];
        s[0] = __expf(s[0] - mx);
        s[1] = __expf(s[1] - mx);
        s[2] = __expf(s[2] - mx);
        s[3] = __expf(s[3] - mx);
        acc_s[mt] = s;
        sum += (s[0] + s[1]) + (s[2] + s[3]);
    }
    sum += __shfl_xor(sum, 16, 64);
    sum += __shfl_xor(sum, 32, 64);
    const float inv = 1.0f / sum;

    // ---- pass 2: O = P' @ V (A = P', B = V^T) ----
    v4f acc_o[4];
    #pragma unroll
    for (int j = 0; j < 4; ++j) acc_o[j] = (v4f){0.f, 0.f, 0.f, 0.f};

    const int vk4 = (tid & 15) * 4;   // staging: key group
    const int vd4 = (tid >> 4) * 4;   // staging: d group
    #pragma unroll
    for (int t = 0; t < 4; ++t) {
        __syncthreads();   // previous tile's LDS reads done
        // write this wave's P' tile: [q = qloc][key = sub*16 + rg*4 + r]
        #pragma unroll
        for (int sub = 0; sub < 4; ++sub) {
            v4f p = acc_s[t * 4 + sub];
            v2h h01, l01, h23, l23;
            cvt_split(p[0], p[1], h01, l01);
            cvt_split(p[2], p[3], h23, l23);
            *(v2h*)&Ph[wave][qloc * 72 + sub * 16 + rg * 4] = h01;
            *(v2h*)&Ph[wave][qloc * 72 + sub * 16 + rg * 4 + 2] = h23;
            *(v2h*)&Pl[wave][qloc * 72 + sub * 16 + rg * 4] = l01;
            *(v2h*)&Pl[wave][qloc * 72 + sub * 16 + rg * 4 + 2] = l23;
        }
        // stage V^T tile: read V[key][d] coalesced, write [d][key]
        {
            v4h rh[4], rl[4];
            #pragma unroll
            for (int i = 0; i < 4; ++i) {
                const float4 vv = *(const float4*)(vbase + (size_t)(b * S + t * 64 + vk4 + i) * 2304 + vd4);
                v2h h0, l0, h1, l1;
                cvt_split(vv.x, vv.y, h0, l0);
                cvt_split(vv.z, vv.w, h1, l1);
                rh[0][i] = h0[0]; rh[1][i] = h0[1]; rh[2][i] = h1[0]; rh[3][i] = h1[1];
                rl[0][i] = l0[0]; rl[1][i] = l0[1]; rl[2][i] = l1[0]; rl[3][i] = l1[1];
            }
            #pragma unroll
            for (int j = 0; j < 4; ++j) {
                *(v4h*)&KVh[(vd4 + j) * 72 + vk4] = rh[j];
                *(v4h*)&KVl[(vd4 + j) * 72 + vk4] = rl[j];
            }
        }
        __syncthreads();
        v8h pah[2], pal[2];
        #pragma unroll
        for (int ks = 0; ks < 2; ++ks) {
            pah[ks] = *(v8h*)&Ph[wave][qloc * 72 + ks * 32 + rg * 8];
            pal[ks] = *(v8h*)&Pl[wave][qloc * 72 + ks * 32 + rg * 8];
        }
        #pragma unroll
        for (int j = 0; j < 4; ++j) {
            v4f acc = acc_o[j];
            #pragma unroll
            for (int ks = 0; ks < 2; ++ks) {
                v8h vbh = *(v8h*)&KVh[(j * 16 + qloc) * 72 + ks * 32 + rg * 8];
                v8h vbl = *(v8h*)&KVl[(j * 16 + qloc) * 72 + ks * 32 + rg * 8];
                acc = __builtin_amdgcn_mfma_f32_16x16x32_f16(pah[ks], vbh, acc, 0, 0, 0);
                acc = __builtin_amdgcn_mfma_f32_16x16x32_f16(pah[ks], vbl, acc, 0, 0, 0);
                acc = __builtin_amdgcn_mfma_f32_16x16x32_f16(pal[ks], vbh, acc, 0, 0, 0);
            }
            acc_o[j] = acc;
        }
    }

    // ---- epilogue: normalize + store. C-layout: row q = rg*4 + r, col d = j*16 + qloc
    #pragma unroll
    for (int r = 0; r < 4; ++r) {
        const float invr = __shfl(inv, rg * 4 + r, 64);
        const size_t row = (size_t)(b * S + qt * 64 + wave * 16 + rg * 4 + r);
        #pragma unroll
        for (int j = 0; j < 4; ++j)
            hout[row * D + head * DH + j * 16 + qloc] = acc_o[j][r] * invr;
    }
}

// ---------------------------------------------------------------------------
// Residual + LayerNorm (in-place), dual-stream via blockIdx.y.
// ---------------------------------------------------------------------------
__global__ __launch_bounds__(256) void ln_res_kernel(
    float* __restrict__ x0, const float* __restrict__ h0,
    const float* __restrict__ g0, const float* __restrict__ bb0,
    float* __restrict__ x1, const float* __restrict__ h1,
    const float* __restrict__ g1, const float* __restrict__ bb1)
{
    float* __restrict__ x = blockIdx.y ? x1 : x0;
    const float* __restrict__ h = blockIdx.y ? h1 : h0;
    const float* __restrict__ g = blockIdx.y ? g1 : g0;
    const float* __restrict__ bb = blockIdx.y ? bb1 : bb0;

    const int row = blockIdx.x;
    const int tid = threadIdx.x;
    const int wave = tid >> 6;
    const int lane = tid & 63;
    __shared__ float red[4];

    float v[3];
    #pragma unroll
    for (int i = 0; i < 3; ++i) {
        int c = tid + 256 * i;
        v[i] = x[(size_t)row * D + c] + h[(size_t)row * D + c];
    }
    float s = v[0] + v[1] + v[2];
    #pragma unroll
    for (int o = 32; o > 0; o >>= 1) s += __shfl_xor(s, o, 64);
    if (lane == 0) red[wave] = s;
    __syncthreads();
    const float mean = (red[0] + red[1] + red[2] + red[3]) * (1.0f / 768.0f);

    float qs = 0.f;
    #pragma unroll
    for (int i = 0; i < 3; ++i) { float d = v[i] - mean; qs += d * d; }
    #pragma unroll
    for (int o = 32; o > 0; o >>= 1) qs += __shfl_xor(qs, o, 64);
    __syncthreads();
    if (lane == 0) red[wave] = qs;
    __syncthreads();
    const float var = (red[0] + red[1] + red[2] + red[3]) * (1.0f / 768.0f);
    const float rstd = rsqrtf(var + 1e-12f);

    #pragma unroll
    for (int i = 0; i < 3; ++i) {
        int c = tid + 256 * i;
        x[(size_t)row * D + c] = (v[i] - mean) * rstd * g[c] + bb[c];
    }
}

// ---------------------------------------------------------------------------
// Host launcher
// ---------------------------------------------------------------------------
extern "C" void kernel_launch(void* const* d_in, const int* in_sizes, int n_in,
                              void* d_out, int out_size, void* d_ws, size_t ws_size,
                              hipStream_t stream)
{
    const float* x    = (const float*)d_in[0];
    const float* y    = (const float*)d_in[1];
    const int*   xm   = (const int*)d_in[2];
    const int*   ym   = (const int*)d_in[3];
    const float* ax_w = (const float*)d_in[4];
    const float* ax_b = (const float*)d_in[5];
    const float* cx_w = (const float*)d_in[6];
    const float* cx_b = (const float*)d_in[7];
    const float* fx_w1 = (const float*)d_in[8];
    const float* fx_b1 = (const float*)d_in[9];
    const float* fx_w2 = (const float*)d_in[10];
    const float* fx_b2 = (const float*)d_in[11];
    const float* ay_w = (const float*)d_in[12];
    const float* ay_b = (const float*)d_in[13];
    const float* cy_w = (const float*)d_in[14];
    const float* cy_b = (const float*)d_in[15];
    const float* fy_w1 = (const float*)d_in[16];
    const float* fy_b1 = (const float*)d_in[17];
    const float* fy_w2 = (const float*)d_in[18];
    const float* fy_b2 = (const float*)d_in[19];
    const float* lnx_g = (const float*)d_in[20];
    const float* lnx_b = (const float*)d_in[21];
    const float* lny_g = (const float*)d_in[22];
    const float* lny_b = (const float*)d_in[23];

    float* xc = (float*)d_out;
    float* yc = xc + (size_t)M * D;

    // Workspace layout. Big (merged) path needs 2 qkv/ffn-mid buffers + 2 hbufs.
    const size_t need = ((size_t)2 * M * D4 + (size_t)2 * M * D) * sizeof(float);
    const bool big = ws_size >= need;
    float* ws0 = (float*)d_ws;
    float* qkvx = ws0;
    float* qkvy = big ? ws0 + (size_t)M * D4 : ws0;
    float* hbx = ws0 + (big ? (size_t)2 * M * D4 : (size_t)M * D4);
    float* hby = big ? hbx + (size_t)M * D : hbx;

    (void)hipMemcpyAsync(xc, x, (size_t)M * D * sizeof(float), hipMemcpyDeviceToDevice, stream);
    (void)hipMemcpyAsync(yc, y, (size_t)M * D * sizeof(float), hipMemcpyDeviceToDevice, stream);

    const dim3 blk(256);
    constexpr int KSPLIT = 4;   // ffn2 split-K factor (grid 192 -> 768 blocks)

    auto qkv_gemm = [&](const float* aq0, const float* akv0, const float* w0, const float* bi0, float* c0,
                        const float* aq1, const float* akv1, const float* w1, const float* bi1, float* c1,
                        int nz) {
        gemm_mfma<<<dim3(2304 / 128, M / 128, nz), blk, 0, stream>>>(
            aq0, akv0, w0, bi0, c0, aq1, akv1, w1, bi1, c1,
            768, D, D, 2304, 768, 2304 / 128, 0, 0);
    };
    auto ffn1_gemm = [&](const float* a0, const float* w0, const float* bi0, float* c0,
                         const float* a1, const float* w1, const float* bi1, float* c1, int nz) {
        gemm_mfma<<<dim3(D4 / 128, M / 128, nz), blk, 0, stream>>>(
            a0, a0, w0, bi0, c0, a1, a1, w1, bi1, c1,
            0, D, D, D4, D4, D4 / 128, 1, 0);
    };
    // split-K ffn2: C must be pre-zeroed; parts atomically accumulate.
    auto ffn2_gemm_split = [&](const float* a0, const float* w0, const float* bi0, float* c0,
                               const float* a1, const float* w1, const float* bi1, float* c1, int nz) {
        gemm_mfma<<<dim3((D / 128) * KSPLIT, M / 128, nz), blk, 0, stream>>>(
            a0, a0, w0, bi0, c0, a1, a1, w1, bi1, c1,
            0, D4, D4 / KSPLIT, D, D, D / 128, 0, 1);
    };
    auto ffn2_gemm_seq = [&](const float* a0, const float* w0, const float* bi0, float* c0,
                             const float* a1, const float* w1, const float* bi1, float* c1, int nz) {
        gemm_mfma<<<dim3(D / 128, M / 128, nz), blk, 0, stream>>>(
            a0, a0, w0, bi0, c0, a1, a1, w1, bi1, c1,
            0, D4, D4, D, D, D / 128, 0, 0);
    };
    auto attn = [&](const float* q0, const int* m0_, float* h0,
                    const float* q1, const int* m1_, float* h1, int nz) {
        attn_kernel<<<dim3(B * H * 4, 1, nz), blk, 0, stream>>>(q0, m0_, h0, q1, m1_, h1);
    };
    auto ln = [&](float* x0, const float* h0, const float* g0, const float* b0,
                  float* x1, const float* h1, const float* g1, const float* b1, int ny) {
        ln_res_kernel<<<dim3(M, ny), blk, 0, stream>>>(x0, h0, g0, b0, x1, h1, g1, b1);
    };

    for (int l = 0; l < L; ++l) {
        const size_t wo = (size_t)l * 3 * D * D;
        const size_t bo = (size_t)l * 3 * D;
        const size_t f1o = (size_t)l * D * D4;
        const size_t f1bo = (size_t)l * D4;
        const size_t f2o = (size_t)l * D4 * D;
        const size_t f2bo = (size_t)l * D;

        if (big) {
            // self-attention x & y merged
            qkv_gemm(xc, xc, ax_w + wo, ax_b + bo, qkvx,
                     yc, yc, ay_w + wo, ay_b + bo, qkvy, 2);
            attn(qkvx, xm, hbx, qkvy, ym, hby, 2);
            ln(xc, hbx, lnx_g, lnx_b, yc, hby, lny_g, lny_b, 2);
            // cross-x (q from xc, kv from yc, mask ym)
            qkv_gemm(xc, yc, cx_w + wo, cx_b + bo, qkvx,
                     xc, yc, cx_w + wo, cx_b + bo, qkvx, 1);
            attn(qkvx, ym, hbx, qkvx, ym, hbx, 1);
            ln(xc, hbx, lnx_g + D, lnx_b + D, xc, hbx, lnx_g + D, lnx_b + D, 1);
            // cross-y (q from yc, kv from updated xc, mask xm)
            qkv_gemm(yc, xc, cy_w + wo, cy_b + bo, qkvy,
                     yc, xc, cy_w + wo, cy_b + bo, qkvy, 1);
            attn(qkvy, xm, hby, qkvy, xm, hby, 1);
            ln(yc, hby, lny_g + D, lny_b + D, yc, hby, lny_g + D, lny_b + D, 1);
            // FFN merged; ffn2 via split-K atomics into zeroed hbx/hby
            ffn1_gemm(xc, fx_w1 + f1o, fx_b1 + f1bo, qkvx,
                      yc, fy_w1 + f1o, fy_b1 + f1bo, qkvy, 2);
            (void)hipMemsetAsync(hbx, 0, (size_t)2 * M * D * sizeof(float), stream);
            ffn2_gemm_split(qkvx, fx_w2 + f2o, fx_b2 + f2bo, hbx,
                            qkvy, fy_w2 + f2o, fy_b2 + f2bo, hby, 2);
            ln(xc, hbx, lnx_g + 2 * D, lnx_b + 2 * D,
               yc, hby, lny_g + 2 * D, lny_b + 2 * D, 2);
        } else {
            // sequential fallback (aliased buffers)
            qkv_gemm(xc, xc, ax_w + wo, ax_b + bo, qkvx, xc, xc, ax_w + wo, ax_b + bo, qkvx, 1);
            attn(qkvx, xm, hbx, qkvx, xm, hbx, 1);
            ln(xc, hbx, lnx_g, lnx_b, xc, hbx, lnx_g, lnx_b, 1);
            qkv_gemm(yc, yc, ay_w + wo, ay_b + bo, qkvy, yc, yc, ay_w + wo, ay_b + bo, qkvy, 1);
            attn(qkvy, ym, hby, qkvy, ym, hby, 1);
            ln(yc, hby, lny_g, lny_b, yc, hby, lny_g, lny_b, 1);
            qkv_gemm(xc, yc, cx_w + wo, cx_b + bo, qkvx, xc, yc, cx_w + wo, cx_b + bo, qkvx, 1);
            attn(qkvx, ym, hbx, qkvx, ym, hbx, 1);
            ln(xc, hbx, lnx_g + D, lnx_b + D, xc, hbx, lnx_g + D, lnx_b + D, 1);
            qkv_gemm(yc, xc, cy_w + wo, cy_b + bo, qkvy, yc, xc, cy_w + wo, cy_b + bo, qkvy, 1);
            attn(qkvy, xm, hby, qkvy, xm, hby, 1);
            ln(yc, hby, lny_g + D, lny_b + D, yc, hby, lny_g + D, lny_b + D, 1);
            ffn1_gemm(xc, fx_w1 + f1o, fx_b1 + f1bo, qkvx, xc, fx_w1 + f1o, fx_b1 + f1bo, qkvx, 1);
            ffn2_gemm_seq(qkvx, fx_w2 + f2o, fx_b2 + f2bo, hbx, qkvx, fx_w2 + f2o, fx_b2 + f2bo, hbx, 1);
            ln(xc, hbx, lnx_g + 2 * D, lnx_b + 2 * D, xc, hbx, lnx_g + 2 * D, lnx_b + 2 * D, 1);
            ffn1_gemm(yc, fy_w1 + f1o, fy_b1 + f1bo, qkvy, yc, fy_w1 + f1o, fy_b1 + f1bo, qkvy, 1);
            ffn2_gemm_seq(qkvy, fy_w2 + f2o, fy_b2 + f2bo, hby, qkvy, fy_w2 + f2o, fy_b2 + f2bo, hby, 1);
            ln(yc, hby, lny_g + 2 * D, lny_b + 2 * D, yc, hby, lny_g + 2 * D, lny_b + 2 * D, 1);
        }
    }
}